// Round 5
// baseline (191.720 us; speedup 1.0000x reference)
//
#include <hip/hip_runtime.h>

#define RESO 128

// ---------------------------------------------------------------------------
// Kernel 1: prefix scans (tiny). ws layout (9 x 128 floats):
//   [0..2]=layers(x,y,z)  [3..5]=a3  [6..8]=a6
// ---------------------------------------------------------------------------
__global__ __launch_bounds__(128) void scan_kernel(
    const float* __restrict__ xL, const float* __restrict__ yL,
    const float* __restrict__ zL, const float* __restrict__ off,
    float* __restrict__ ws)
{
    __shared__ float s_tmp[4];
    __shared__ float s_a3[RESO];

    const int tid  = threadIdx.x;
    const int lane = tid & 63;
    const int wave = tid >> 6;

    for (int ax = 0; ax < 3; ++ax) {
        const float* L = (ax == 0) ? xL : (ax == 1) ? yL : zL;
        const float li   = L[tid];
        const float lim1 = (tid > 0) ? L[tid - 1] : 0.f;

        float v = (tid == 0) ? 0.f : 2.f * lim1 + 2.f * li;
        #pragma unroll
        for (int o = 1; o < 64; o <<= 1) {
            float u = __shfl_up(v, o, 64);
            if (lane >= o) v += u;
        }
        if (lane == 63) s_tmp[wave] = v;
        __syncthreads();
        if (wave == 1) v += s_tmp[0];
        const float a3v = off[ax] + v;
        s_a3[tid] = a3v;
        __syncthreads();

        const float a3m1 = (tid > 0) ? s_a3[tid - 1] : 0.f;
        float w = (tid == 0) ? 0.f : 3.f * lim1 + li + 2.f * a3m1;
        #pragma unroll
        for (int o = 1; o < 64; o <<= 1) {
            float u = __shfl_up(w, o, 64);
            if (lane >= o) w += u;
        }
        if (lane == 63) s_tmp[2 + wave] = w;
        __syncthreads();
        if (wave == 1) w += s_tmp[2];

        ws[ax * RESO + tid]       = li;
        ws[(3 + ax) * RESO + tid] = a3v;
        ws[(6 + ax) * RESO + tid] = w;
        __syncthreads();
    }
}

// ---------------------------------------------------------------------------
// Kernel 2: fused main pass. Tables packed in LDS:
//   tabS[ax][i] = (L, a3, a6, 0)  -> sdf does 3x ds_read_b128 per point
//   tabR[ax][i] = (L, a3)         -> render does 3x ds_read_b64 per point
// 4 sdf + 4 render points per thread, float4/int4 global access.
// Grid-stride with 2048 blocks (8/CU resident): one LDS fill, 2 iterations.
// rsq replaces sqrt+div (threshold 2.21 >> rsq error).
// ---------------------------------------------------------------------------
__global__ __launch_bounds__(256) void fused_kernel(
    const float* __restrict__ renderPts, const int* __restrict__ renderIdx,
    const float* __restrict__ sdfPts,    const int* __restrict__ sdfIdx,
    const float* __restrict__ ws,        const float* __restrict__ off,
    float* __restrict__ sdfOut, float* __restrict__ nrmOut, int N)
{
    __shared__ float4 tabS[3][RESO];
    __shared__ float2 tabR[3][RESO];

    const int tid = threadIdx.x;
    if (tid < RESO) {
        #pragma unroll
        for (int ax = 0; ax < 3; ++ax) {
            const float L  = ws[ax * RESO + tid];
            const float a3 = ws[(3 + ax) * RESO + tid];
            const float a6 = ws[(6 + ax) * RESO + tid];
            tabS[ax][tid] = make_float4(L, a3, a6, 0.f);
            tabR[ax][tid] = make_float2(L, a3);
        }
    }
    __syncthreads();

    const float off3 = off[3];
    const int Ng  = N >> 2;
    const int rem = N & 3;
    const int total = Ng + (rem ? 1 : 0);
    const int stride = gridDim.x * blockDim.x;

    for (int t = blockIdx.x * blockDim.x + tid; t < total; t += stride) {
        if (t < Ng) {
            // ---------------- sdf: 4 points ----------------
            const int4   sid = ((const int4*)sdfIdx)[t];
            const float4 sp0 = ((const float4*)sdfPts)[3 * t + 0];
            const float4 sp1 = ((const float4*)sdfPts)[3 * t + 1];
            const float4 sp2 = ((const float4*)sdfPts)[3 * t + 2];
            const float px[4] = {sp0.x, sp0.w, sp1.z, sp2.y};
            const float py[4] = {sp0.y, sp1.x, sp1.w, sp2.z};
            const float pz[4] = {sp0.z, sp1.y, sp2.x, sp2.w};
            const int  ids[4] = {sid.x, sid.y, sid.z, sid.w};

            float sv[4];
            #pragma unroll
            for (int k = 0; k < 4; ++k) {
                const int id = ids[k];
                const float4 tx = tabS[0][id & 127];
                const float4 ty = tabS[1][(id >> 7) & 127];
                const float4 tz = tabS[2][(id >> 14) & 127];
                const float a0 = tx.x * px[k];
                const float a1 = ty.x * py[k];
                const float a2 = tz.x * pz[k];
                const float a6 = off3 + tx.z + ty.z + tz.z;
                const float num = (a0 + tx.y) * px[k] + (a1 + ty.y) * py[k]
                                + (a2 + tz.y) * pz[k] + a6;
                const float dx = 2.f * a0 + tx.y;
                const float dy = 2.f * a1 + ty.y;
                const float dz = 2.f * a2 + tz.y;
                const float d2 = dx * dx + dy * dy + dz * dz;
                sv[k] = num * __builtin_amdgcn_rsqf(d2) * (1.0f / (float)RESO);
            }
            ((float4*)sdfOut)[t] = make_float4(sv[0], sv[1], sv[2], sv[3]);

            // ---------------- render: 4 points ----------------
            const int4   rid = ((const int4*)renderIdx)[t];
            const float4 rp0 = ((const float4*)renderPts)[3 * t + 0];
            const float4 rp1 = ((const float4*)renderPts)[3 * t + 1];
            const float4 rp2 = ((const float4*)renderPts)[3 * t + 2];
            const float rx[4] = {rp0.x, rp0.w, rp1.z, rp2.y};
            const float ry[4] = {rp0.y, rp1.x, rp1.w, rp2.z};
            const float rz[4] = {rp0.z, rp1.y, rp2.x, rp2.w};
            const int  jds[4] = {rid.x, rid.y, rid.z, rid.w};

            float nx[4], ny[4], nz[4];
            #pragma unroll
            for (int k = 0; k < 4; ++k) {
                const int id = jds[k];
                const float2 ux = tabR[0][id & 127];
                const float2 uy = tabR[1][(id >> 7) & 127];
                const float2 uz = tabR[2][(id >> 14) & 127];
                const float x = 2.f * ux.x * rx[k] + ux.y;
                const float y = 2.f * uy.x * ry[k] + uy.y;
                const float z = 2.f * uz.x * rz[k] + uz.y;
                const float n2 = x * x + y * y + z * z;
                const float inv = __builtin_amdgcn_rsqf(fmaxf(n2, 1e-24f));
                nx[k] = x * inv; ny[k] = y * inv; nz[k] = z * inv;
            }
            float4* no = (float4*)nrmOut;
            no[3 * t + 0] = make_float4(nx[0], ny[0], nz[0], nx[1]);
            no[3 * t + 1] = make_float4(ny[1], nz[1], nx[2], ny[2]);
            no[3 * t + 2] = make_float4(nz[2], nx[3], ny[3], nz[3]);
        } else {
            // ---------------- tail (N not divisible by 4) ----------------
            for (int r = 0; r < rem; ++r) {
                const int i = 4 * Ng + r;
                {
                    const int id = sdfIdx[i];
                    const float4 tx = tabS[0][id & 127];
                    const float4 ty = tabS[1][(id >> 7) & 127];
                    const float4 tz = tabS[2][(id >> 14) & 127];
                    const float px_ = sdfPts[3 * i], py_ = sdfPts[3 * i + 1], pz_ = sdfPts[3 * i + 2];
                    const float a0 = tx.x * px_;
                    const float a1 = ty.x * py_;
                    const float a2 = tz.x * pz_;
                    const float a6 = off3 + tx.z + ty.z + tz.z;
                    const float num = (a0 + tx.y) * px_ + (a1 + ty.y) * py_
                                    + (a2 + tz.y) * pz_ + a6;
                    const float dx = 2.f * a0 + tx.y;
                    const float dy = 2.f * a1 + ty.y;
                    const float dz = 2.f * a2 + tz.y;
                    const float d2 = dx * dx + dy * dy + dz * dz;
                    sdfOut[i] = num * __builtin_amdgcn_rsqf(d2) * (1.0f / (float)RESO);
                }
                {
                    const int id = renderIdx[i];
                    const float2 ux = tabR[0][id & 127];
                    const float2 uy = tabR[1][(id >> 7) & 127];
                    const float2 uz = tabR[2][(id >> 14) & 127];
                    const float rx_ = renderPts[3 * i], ry_ = renderPts[3 * i + 1], rz_ = renderPts[3 * i + 2];
                    const float x = 2.f * ux.x * rx_ + ux.y;
                    const float y = 2.f * uy.x * ry_ + uy.y;
                    const float z = 2.f * uz.x * rz_ + uz.y;
                    const float n2 = x * x + y * y + z * z;
                    const float inv = __builtin_amdgcn_rsqf(fmaxf(n2, 1e-24f));
                    nrmOut[3 * i] = x * inv; nrmOut[3 * i + 1] = y * inv; nrmOut[3 * i + 2] = z * inv;
                }
            }
        }
    }
}

// ---------------------------------------------------------------------------
// Inputs (setup_inputs order):
//  0 renderPointList (N*3 f32)   1 renderIndexList (N i32)
//  2 sdfPointList    (N*3 f32)   3 sdfIndexList    (N i32)
//  4 xLayer (128 f32) 5 yLayer (128 f32) 6 zLayer (128 f32) 7 offset (4 f32)
// Output: sdfList (N f32) ++ normalList (N*3 f32)
// ---------------------------------------------------------------------------
extern "C" void kernel_launch(void* const* d_in, const int* in_sizes, int n_in,
                              void* d_out, int out_size, void* d_ws, size_t ws_size,
                              hipStream_t stream)
{
    const float* renderPts = (const float*)d_in[0];
    const int*   renderIdx = (const int*)d_in[1];
    const float* sdfPts    = (const float*)d_in[2];
    const int*   sdfIdx    = (const int*)d_in[3];
    const float* xL        = (const float*)d_in[4];
    const float* yL        = (const float*)d_in[5];
    const float* zL        = (const float*)d_in[6];
    const float* off       = (const float*)d_in[7];

    float* ws  = (float*)d_ws;
    float* out = (float*)d_out;
    const int N = in_sizes[1];

    scan_kernel<<<1, 128, 0, stream>>>(xL, yL, zL, off, ws);

    // 2048 blocks = 8 blocks/CU x 256 CUs, grid-stride covers all groups.
    fused_kernel<<<2048, 256, 0, stream>>>(renderPts, renderIdx, sdfPts, sdfIdx,
                                           ws, off, out, out + N, N);
}

// Round 6
// 187.499 us; speedup vs baseline: 1.0225x; 1.0225x over previous
//
#include <hip/hip_runtime.h>

#define RESO 128

// ---------------------------------------------------------------------------
// Kernel 1: prefix scans (tiny). ws layout (9 x 128 floats):
//   [0..2]=layers(x,y,z)  [3..5]=a3  [6..8]=a6
// ---------------------------------------------------------------------------
__global__ __launch_bounds__(128) void scan_kernel(
    const float* __restrict__ xL, const float* __restrict__ yL,
    const float* __restrict__ zL, const float* __restrict__ off,
    float* __restrict__ ws)
{
    __shared__ float s_tmp[4];
    __shared__ float s_a3[RESO];

    const int tid  = threadIdx.x;
    const int lane = tid & 63;
    const int wave = tid >> 6;

    for (int ax = 0; ax < 3; ++ax) {
        const float* L = (ax == 0) ? xL : (ax == 1) ? yL : zL;
        const float li   = L[tid];
        const float lim1 = (tid > 0) ? L[tid - 1] : 0.f;

        float v = (tid == 0) ? 0.f : 2.f * lim1 + 2.f * li;
        #pragma unroll
        for (int o = 1; o < 64; o <<= 1) {
            float u = __shfl_up(v, o, 64);
            if (lane >= o) v += u;
        }
        if (lane == 63) s_tmp[wave] = v;
        __syncthreads();
        if (wave == 1) v += s_tmp[0];
        const float a3v = off[ax] + v;
        s_a3[tid] = a3v;
        __syncthreads();

        const float a3m1 = (tid > 0) ? s_a3[tid - 1] : 0.f;
        float w = (tid == 0) ? 0.f : 3.f * lim1 + li + 2.f * a3m1;
        #pragma unroll
        for (int o = 1; o < 64; o <<= 1) {
            float u = __shfl_up(w, o, 64);
            if (lane >= o) w += u;
        }
        if (lane == 63) s_tmp[2 + wave] = w;
        __syncthreads();
        if (wave == 1) w += s_tmp[2];

        ws[ax * RESO + tid]       = li;
        ws[(3 + ax) * RESO + tid] = a3v;
        ws[(6 + ax) * RESO + tid] = w;
        __syncthreads();
    }
}

// ---------------------------------------------------------------------------
// Kernel 2: fused main pass, ONE point per thread per list.
// Per-thread chain: idx dword (4 lines/wave) + point dwordx3 (12 lines,
// fully used) + 3 LDS b128 gathers + ~30 VALU + dword / dwordx3 store.
// sdf and render sections independent -> ILP. 16384 blocks, no grid-stride.
// Table: single float4 (L, a3, a6, 0) per axis entry, 6 KB LDS.
// ---------------------------------------------------------------------------
__global__ __launch_bounds__(256) void fused_kernel(
    const float* __restrict__ renderPts, const int* __restrict__ renderIdx,
    const float* __restrict__ sdfPts,    const int* __restrict__ sdfIdx,
    const float* __restrict__ ws,        const float* __restrict__ off,
    float* __restrict__ sdfOut, float* __restrict__ nrmOut, int N)
{
    __shared__ float4 tab[3][RESO];

    const int tid = threadIdx.x;
    if (tid < RESO) {
        #pragma unroll
        for (int ax = 0; ax < 3; ++ax)
            tab[ax][tid] = make_float4(ws[ax * RESO + tid],
                                       ws[(3 + ax) * RESO + tid],
                                       ws[(6 + ax) * RESO + tid], 0.f);
    }
    __syncthreads();

    const int i = blockIdx.x * blockDim.x + tid;
    if (i >= N) return;

    const float off3 = off[3];

    // ---------------- sdf ----------------
    const int sid = sdfIdx[i];
    const float px = sdfPts[3 * i + 0];
    const float py = sdfPts[3 * i + 1];
    const float pz = sdfPts[3 * i + 2];
    const float4 tx = tab[0][sid & 127];
    const float4 ty = tab[1][(sid >> 7) & 127];
    const float4 tz = tab[2][(sid >> 14) & 127];

    const float a0 = tx.x * px;
    const float a1 = ty.x * py;
    const float a2 = tz.x * pz;
    const float a6 = off3 + tx.z + ty.z + tz.z;
    const float num = (a0 + tx.y) * px + (a1 + ty.y) * py + (a2 + tz.y) * pz + a6;
    const float dx = 2.f * a0 + tx.y;
    const float dy = 2.f * a1 + ty.y;
    const float dz = 2.f * a2 + tz.y;
    const float d2 = dx * dx + dy * dy + dz * dz;
    sdfOut[i] = num * __builtin_amdgcn_rsqf(d2) * (1.0f / (float)RESO);

    // ---------------- render ----------------
    const int rid = renderIdx[i];
    const float rx = renderPts[3 * i + 0];
    const float ry = renderPts[3 * i + 1];
    const float rz = renderPts[3 * i + 2];
    const float4 ux = tab[0][rid & 127];
    const float4 uy = tab[1][(rid >> 7) & 127];
    const float4 uz = tab[2][(rid >> 14) & 127];

    const float x = 2.f * ux.x * rx + ux.y;
    const float y = 2.f * uy.x * ry + uy.y;
    const float z = 2.f * uz.x * rz + uz.y;
    const float n2 = x * x + y * y + z * z;
    const float inv = __builtin_amdgcn_rsqf(fmaxf(n2, 1e-24f));
    nrmOut[3 * i + 0] = x * inv;
    nrmOut[3 * i + 1] = y * inv;
    nrmOut[3 * i + 2] = z * inv;
}

// ---------------------------------------------------------------------------
// Inputs (setup_inputs order):
//  0 renderPointList (N*3 f32)   1 renderIndexList (N i32)
//  2 sdfPointList    (N*3 f32)   3 sdfIndexList    (N i32)
//  4 xLayer (128 f32) 5 yLayer (128 f32) 6 zLayer (128 f32) 7 offset (4 f32)
// Output: sdfList (N f32) ++ normalList (N*3 f32)
// ---------------------------------------------------------------------------
extern "C" void kernel_launch(void* const* d_in, const int* in_sizes, int n_in,
                              void* d_out, int out_size, void* d_ws, size_t ws_size,
                              hipStream_t stream)
{
    const float* renderPts = (const float*)d_in[0];
    const int*   renderIdx = (const int*)d_in[1];
    const float* sdfPts    = (const float*)d_in[2];
    const int*   sdfIdx    = (const int*)d_in[3];
    const float* xL        = (const float*)d_in[4];
    const float* yL        = (const float*)d_in[5];
    const float* zL        = (const float*)d_in[6];
    const float* off       = (const float*)d_in[7];

    float* ws  = (float*)d_ws;
    float* out = (float*)d_out;
    const int N = in_sizes[1];

    scan_kernel<<<1, 128, 0, stream>>>(xL, yL, zL, off, ws);

    const int block = 256;
    const int grid = (N + block - 1) / block;   // 16384 @ N=4.19M
    fused_kernel<<<grid, block, 0, stream>>>(renderPts, renderIdx, sdfPts, sdfIdx,
                                             ws, off, out, out + N, N);
}